// Round 11
// baseline (142.989 us; speedup 1.0000x reference)
//
#include <hip/hip_runtime.h>
#include <math.h>

constexpr int Bb = 2;
constexpr int Nn = 2048;
constexpr int Cc = 512;
constexpr int Hh = 8;
constexpr int Dd = 64;

typedef short short8 __attribute__((ext_vector_type(8)));
typedef float floatx4 __attribute__((ext_vector_type(4)));
typedef float floatx16 __attribute__((ext_vector_type(16)));

__device__ inline short8 bcs8(uint4 u) { return __builtin_bit_cast(short8, u); }

__device__ inline floatx4 mfma16(short8 a, short8 b, floatx4 c) {
    return __builtin_amdgcn_mfma_f32_16x16x32_bf16(a, b, c, 0, 0, 0);
}
__device__ inline floatx16 mfma32(short8 a, short8 b, floatx16 c) {
    return __builtin_amdgcn_mfma_f32_32x32x16_bf16(a, b, c, 0, 0, 0);
}

#if __has_builtin(__builtin_amdgcn_exp2f)
#define EXP2(x) __builtin_amdgcn_exp2f(x)
#else
#define EXP2(x) __expf((x) * 0.69314718056f)
#endif

// pack bf16(a)|bf16(b)<<16, truncation (hi/lo splits: lo compensates hi)
__device__ inline unsigned pk_trunc(float a, float b) {
    return __builtin_amdgcn_perm(__float_as_uint(b), __float_as_uint(a), 0x07060302u);
}
// RNE pack
__device__ inline unsigned pk_rne(float a, float b) {
    unsigned ua = __float_as_uint(a); ua += 0x7fffu + ((ua >> 16) & 1u);
    unsigned ub = __float_as_uint(b); ub += 0x7fffu + ((ub >> 16) & 1u);
    return __builtin_amdgcn_perm(ub, ua, 0x07060302u);
}
__device__ inline unsigned short rne1(float a) {
    unsigned u = __float_as_uint(a); u += 0x7fffu + ((u >> 16) & 1u);
    return (unsigned short)(u >> 16);
}
__device__ inline float tr16(float a) {
    return __uint_as_float(__float_as_uint(a) & 0xffff0000u);
}
__device__ inline void split8(float4 A, float4 B, uint4& hi, uint4& lo) {
    hi = make_uint4(pk_trunc(A.x, A.y), pk_trunc(A.z, A.w),
                    pk_trunc(B.x, B.y), pk_trunc(B.z, B.w));
    lo = make_uint4(pk_trunc(A.x - tr16(A.x), A.y - tr16(A.y)),
                    pk_trunc(A.z - tr16(A.z), A.w - tr16(A.w)),
                    pk_trunc(B.x - tr16(B.x), B.y - tr16(B.y)),
                    pk_trunc(B.z - tr16(B.z), B.w - tr16(B.w)));
}

// Fragment-major layout (16x16x32 MFMA operand):
//   frag(idx, kc, comp): 1 KB at (((idx*16 + kc)*2 + comp) * 512) shorts;
//   lane l holds elem[row l&15][k kc*32 + (l>>4)*8 + jj], 8 bf16 = 16 B.

// ---------------------------------------------------------------------------
// prep: bid<256 -> weights transpose+split -> B-frag-major wqfrag/wpfrag;
//       bid>=256 -> x split -> A-frag-major xfrag (hi/lo).
// ---------------------------------------------------------------------------
__global__ __launch_bounds__(256) void prep(const float* __restrict__ qkv_w,
                                            const float* __restrict__ proj_w,
                                            const float* __restrict__ x,
                                            unsigned short* __restrict__ wqfrag,
                                            unsigned short* __restrict__ wpfrag,
                                            unsigned short* __restrict__ xfrag)
{
    __shared__ float Tl[64][68];
    int bid = blockIdx.x;
    int t = threadIdx.x;
    if (bid >= 256) {                      // ---- x -> A-frag split ----
        int xb = bid - 256;                // 0..255
        int tok = xb * 16 + (t >> 4);      // 16 tokens/block
        int kc = t & 15;                   // k-chunk of 32
        const float* px = x + (size_t)tok * 512 + kc * 32;
        uint4 h[4], l[4];
        #pragma unroll
        for (int o = 0; o < 4; ++o) {
            float4 fa = *(const float4*)(px + o * 8);
            float4 fb = *(const float4*)(px + o * 8 + 4);
            split8(fa, fb, h[o], l[o]);
        }
        int mt = tok >> 4, m = tok & 15;
        unsigned short* fb_ = xfrag + ((size_t)(mt * 16 + kc) * 2) * 512;
        #pragma unroll
        for (int o = 0; o < 4; ++o) {
            *(uint4*)(fb_ + (m + 16 * o) * 8) = h[o];
            *(uint4*)(fb_ + 512 + (m + 16 * o) * 8) = l[o];
        }
        return;
    }
    // ---- weight transpose + split -> B-frag-major ----
    const float* src; unsigned short* dfrag; int W, f0, k0;
    if (bid < 192) { int kt = bid / 24, ft = bid % 24; W = 1536; src = qkv_w; dfrag = wqfrag; f0 = ft * 64; k0 = kt * 64; }
    else { int b2 = bid - 192; int kt = b2 / 8, ft = b2 % 8; W = 512; src = proj_w; dfrag = wpfrag; f0 = ft * 64; k0 = kt * 64; }
    {
        int kl = t >> 2, fc = (t & 3) * 16;
        const float* p = src + (size_t)(k0 + kl) * W + f0 + fc;
        #pragma unroll
        for (int i = 0; i < 4; ++i) {
            float4 v = *(const float4*)(p + i * 4);
            Tl[kl][fc + i * 4 + 0] = v.x; Tl[kl][fc + i * 4 + 1] = v.y;
            Tl[kl][fc + i * 4 + 2] = v.z; Tl[kl][fc + i * 4 + 3] = v.w;
        }
    }
    __syncthreads();
    {
        int fl = t >> 2, kc16 = (t & 3) * 16;
        float v[16];
        #pragma unroll
        for (int i = 0; i < 16; ++i) v[i] = Tl[kc16 + i][fl];
        unsigned hi[8], lo[8];
        #pragma unroll
        for (int i = 0; i < 8; ++i) {
            float a = v[2 * i], b = v[2 * i + 1];
            hi[i] = pk_trunc(a, b);
            lo[i] = pk_trunc(a - tr16(a), b - tr16(b));
        }
        int f = f0 + fl;
        int nt = f >> 4, nin = f & 15;
        int kc = (k0 + kc16) >> 5;
        int oct0 = (kc16 >> 3) & 3;        // 0 or 2
        unsigned short* fb_ = dfrag + ((size_t)(nt * 16 + kc) * 2) * 512;
        *(uint4*)(fb_ + (nin + 16 * oct0) * 8) = make_uint4(hi[0], hi[1], hi[2], hi[3]);
        *(uint4*)(fb_ + (nin + 16 * (oct0 + 1)) * 8) = make_uint4(hi[4], hi[5], hi[6], hi[7]);
        *(uint4*)(fb_ + 512 + (nin + 16 * oct0) * 8) = make_uint4(lo[0], lo[1], lo[2], lo[3]);
        *(uint4*)(fb_ + 512 + (nin + 16 * (oct0 + 1)) * 8) = make_uint4(lo[4], lo[5], lo[6], lo[7]);
    }
}

// ---------------------------------------------------------------------------
// GEMM1: barrier-free, zero-LDS. Block = 128 tok x 128 cols; 8 waves
// (wm2 x wn4), each 4 mt x 2 nt of split-bf16 MFMA streaming dense frags.
// grid (12, 32). Outputs: qd row-major (pre-scaled 0.125*log2e), kfrag
// (32x32x16 A-op frag-major), vfrag (PV A-op frag-major).
// ---------------------------------------------------------------------------
__global__ __launch_bounds__(512, 4) void gemm_qkv(const unsigned short* __restrict__ xfrag,
                                                   const unsigned short* __restrict__ wqfrag,
                                                   unsigned short* __restrict__ qd,
                                                   unsigned short* __restrict__ kfrag,
                                                   unsigned short* __restrict__ vfrag)
{
    const int tid = threadIdx.x, lane = tid & 63, w = tid >> 6;
    const int l15 = lane & 15, l4 = lane >> 4;
    const int wm = w >> 2, wn = w & 3;
    const int row0 = blockIdx.y * 128, col0 = blockIdx.x * 128;
    const int mt0 = (row0 >> 4) + wm * 4;  // 4 consecutive mt
    const int nt0 = (col0 >> 4) + wn * 2;  // 2 consecutive nt per wave

    floatx4 acc[4][2];
    #pragma unroll
    for (int i = 0; i < 4; ++i)
        #pragma unroll
        for (int j = 0; j < 2; ++j)
            #pragma unroll
            for (int r = 0; r < 4; ++r) acc[i][j][r] = 0.f;

    const unsigned short* xb = xfrag + (size_t)lane * 8;
    const unsigned short* wb = wqfrag + (size_t)lane * 8;

    #pragma unroll
    for (int kc = 0; kc < 16; ++kc) {
        short8 bf[2][2];
        #pragma unroll
        for (int nt = 0; nt < 2; ++nt) {
            size_t fb_ = ((size_t)((nt0 + nt) * 16 + kc) * 2) * 512;
            bf[nt][0] = bcs8(*(const uint4*)(wb + fb_));
            bf[nt][1] = bcs8(*(const uint4*)(wb + fb_ + 512));
        }
        #pragma unroll
        for (int mt = 0; mt < 4; ++mt) {
            size_t fa_ = ((size_t)((mt0 + mt) * 16 + kc) * 2) * 512;
            short8 ah = bcs8(*(const uint4*)(xb + fa_));
            short8 al = bcs8(*(const uint4*)(xb + fa_ + 512));
            #pragma unroll
            for (int nt = 0; nt < 2; ++nt) {
                acc[mt][nt] = mfma16(ah, bf[nt][0], acc[mt][nt]);
                acc[mt][nt] = mfma16(ah, bf[nt][1], acc[mt][nt]);
                acc[mt][nt] = mfma16(al, bf[nt][0], acc[mt][nt]);
            }
        }
    }
    // epilogue: q row-major (scaled); K scatter to kfrag; V dense to vfrag.
    #pragma unroll
    for (int mt = 0; mt < 4; ++mt)
        #pragma unroll
        for (int nt = 0; nt < 2; ++nt) {
            int c = col0 + (wn * 2 + nt) * 16 + l15;     // 0..1535
            int which = c >> 9;                          // 0=q,1=k,2=v
            int head = (c >> 6) & 7, d = c & 63;
            int tokb = row0 + (wm * 4 + mt) * 16 + l4 * 4;
            int b = tokb >> 11, n = tokb & 2047;
            int bh = b * 8 + head;
            if (which == 0) {
                #pragma unroll
                for (int r = 0; r < 4; ++r)
                    qd[(size_t)(bh * 2048 + n + r) * 64 + d] = rne1(acc[mt][nt][r] * 0.18033688f);
            } else if (which == 1) {
                int s = d >> 4;
                size_t fb_ = ((size_t)(bh * 64 + (n >> 5)) * 4 + s) * 512 + (d & 7);
                int hl = ((d >> 3) & 1) * 32;
                #pragma unroll
                for (int r = 0; r < 4; ++r)
                    kfrag[fb_ + (size_t)(hl + ((n + r) & 31)) * 8] = rne1(acc[mt][nt][r]);
            } else {
                int j = n >> 4, mtv = d >> 5;
                uint2 pv;
                pv.x = pk_rne(acc[mt][nt][0], acc[mt][nt][1]);
                pv.y = pk_rne(acc[mt][nt][2], acc[mt][nt][3]);
                *(uint2*)&vfrag[((size_t)(bh * 128 + j) * 2 + mtv) * 512 +
                                (size_t)(((n >> 3) & 1) * 32 + (d & 31)) * 8 + (n & 7)] = pv;
            }
        }
}

// ---------------------------------------------------------------------------
// Attention: barrier-free frag-load K-loop; 512 thr = 8 waves (qg2 x kg4).
// Grid 512 = 16 bh x 32 qtiles (64 q), XCD-swizzled. The two qg-waves of a
// kg share the SAME K/V strip -> duplicate fragment loads hit L1 (halved L2
// traffic). S^T = K.Q^T (mfma32, log2e in Q -> exp2); P trunc-packed; l via
// all-ones MFMA; 2-shuffle P transform. qg-segmented LDS merge at end;
// epilogue writes O A-frag-major (hi/lo) honoring the buggy reshape.
// ---------------------------------------------------------------------------
__global__ __launch_bounds__(512, 4) void attn(const unsigned short* __restrict__ qd,
                                               const unsigned short* __restrict__ kfrag,
                                               const unsigned short* __restrict__ vfrag,
                                               unsigned short* __restrict__ Ofrag)
{
    __shared__ __align__(16) float Ms[2][2048];   // per-qg [d(64)][q(32)]
    __shared__ float Ls[2][64];                   // per-qg [h(2)][q(32)]
    __shared__ float Ts[2][2176];                 // per-qg [q(32)][68]

    int bid = blockIdx.x;
    int xcd = bid & 7; int rr = bid >> 3;
    int qt = rr & 31; int bhi = rr >> 5;
    int bh = (bhi << 3) | xcd;
    int tid = threadIdx.x, lane = tid & 63, w = tid >> 6;
    int qg = w >> 2, kg = w & 3;
    int l31 = lane & 31, h = lane >> 5;

    // Q^T fragments (B-operand), once (pre-scaled, log2e folded)
    short8 qf[4];
    #pragma unroll
    for (int s = 0; s < 4; ++s)
        qf[s] = bcs8(*(const uint4*)(qd + ((size_t)bh * 2048 + qt * 64 + qg * 32 + l31) * 64 + s * 16 + h * 8));

    const uint4 onesu = make_uint4(0x3F803F80u, 0x3F803F80u, 0x3F803F80u, 0x3F803F80u);
    const short8 onesf = bcs8(onesu);

    floatx16 OT[2], OTl;
    #pragma unroll
    for (int i = 0; i < 2; ++i)
        #pragma unroll
        for (int r = 0; r < 16; ++r) OT[i][r] = 0.f;
    #pragma unroll
    for (int r = 0; r < 16; ++r) OTl[r] = 0.f;

    const unsigned short* kb_ = kfrag + ((size_t)(bh * 64 + kg * 16) * 4) * 512 + lane * 8;
    const unsigned short* vb_ = vfrag + ((size_t)(bh * 128 + kg * 32) * 2) * 512 + lane * 8;

    #pragma unroll
    for (int c = 0; c < 16; ++c) {
        uint4 kfu[4];
        #pragma unroll
        for (int s = 0; s < 4; ++s)
            kfu[s] = *(const uint4*)(kb_ + ((size_t)c * 4 + s) * 512);
        uint4 vfu[2][2];
        #pragma unroll
        for (int kc = 0; kc < 2; ++kc)
            #pragma unroll
            for (int mtv = 0; mtv < 2; ++mtv)
                vfu[kc][mtv] = *(const uint4*)(vb_ + ((size_t)(c * 2 + kc) * 2 + mtv) * 512);

        floatx16 st;
        #pragma unroll
        for (int r = 0; r < 16; ++r) st[r] = 0.f;
        #pragma unroll
        for (int s = 0; s < 4; ++s) st = mfma32(bcs8(kfu[s]), qf[s], st);

        unsigned P2[8];
        #pragma unroll
        for (int s2 = 0; s2 < 8; ++s2)
            P2[s2] = pk_trunc(EXP2(st[2 * s2]), EXP2(st[2 * s2 + 1]));

        #pragma unroll
        for (int kc = 0; kc < 2; ++kc) {
            unsigned X0 = P2[4 * kc + 0], X1 = P2[4 * kc + 1];
            unsigned Y0 = P2[4 * kc + 2], Y1 = P2[4 * kc + 3];
            unsigned T0 = h ? X0 : Y0;
            unsigned T1 = h ? X1 : Y1;
            unsigned To0 = __shfl_xor(T0, 32, 64);
            unsigned To1 = __shfl_xor(T1, 32, 64);
            uint4 fu;
            fu.x = h ? To0 : X0;
            fu.y = h ? To1 : X1;
            fu.z = h ? Y0 : To0;
            fu.w = h ? Y1 : To1;
            short8 pf = bcs8(fu);
            OT[0] = mfma32(bcs8(vfu[kc][0]), pf, OT[0]);
            OT[1] = mfma32(bcs8(vfu[kc][1]), pf, OT[1]);
            OTl = mfma32(onesf, pf, OTl);         // l += column-sums of rounded P
        }
    }

    // ---- merge partial O/l across the 4 kg waves, per qg segment ----
    float* Mq = Ms[qg];
    float* Lq = Ls[qg];
    float* Tq = Ts[qg];

    if (kg == 3) {
        #pragma unroll
        for (int mtv = 0; mtv < 2; ++mtv)
            #pragma unroll
            for (int r = 0; r < 16; ++r) {
                int d = mtv * 32 + (r & 3) + 8 * (r >> 2) + 4 * h;
                Mq[d * 32 + l31] = OT[mtv][r];
            }
        Lq[h * 32 + l31] = OTl[0];
    }
    __syncthreads();
    if (kg == 2) {
        #pragma unroll
        for (int mtv = 0; mtv < 2; ++mtv)
            #pragma unroll
            for (int r = 0; r < 16; ++r) {
                int d = mtv * 32 + (r & 3) + 8 * (r >> 2) + 4 * h;
                Mq[d * 32 + l31] += OT[mtv][r];
            }
        Lq[h * 32 + l31] += OTl[0];
    }
    __syncthreads();
    if (kg == 1) {
        #pragma unroll
        for (int mtv = 0; mtv < 2; ++mtv)
            #pragma unroll
            for (int r = 0; r < 16; ++r) {
                int d = mtv * 32 + (r & 3) + 8 * (r >> 2) + 4 * h;
                Mq[d * 32 + l31] += OT[mtv][r];
            }
        Lq[h * 32 + l31] += OTl[0];
    }
    __syncthreads();
    if (kg == 0) {
        #pragma unroll
        for (int mtv = 0; mtv < 2; ++mtv)
            #pragma unroll
            for (int r = 0; r < 16; ++r) {
                int d = mtv * 32 + (r & 3) + 8 * (r >> 2) + 4 * h;
                OT[mtv][r] += Mq[d * 32 + l31];
            }
        float inv = 1.f / (Lq[h * 32 + l31] + OTl[0]);      // halves are duplicates
        #pragma unroll
        for (int mtv = 0; mtv < 2; ++mtv)
            #pragma unroll
            for (int r = 0; r < 16; ++r) {
                int d = mtv * 32 + (r & 3) + 8 * (r >> 2) + 4 * h;
                Tq[l31 * 68 + d] = OT[mtv][r] * inv;
            }
    }
    __syncthreads();
    // all 512 threads: split-bf16 store of O into A-frag-major Ofrag
    {
        int q = tid >> 3, dc = (tid & 7) * 8;               // q 0..63
        const float* T = Ts[q >> 5];
        int ql = q & 31;
        float vv[8];
        #pragma unroll
        for (int i = 0; i < 8; ++i) vv[i] = T[ql * 68 + dc + i];
        unsigned hi[4], lo[4];
        #pragma unroll
        for (int i = 0; i < 4; ++i) {
            float a = vv[2 * i], bb = vv[2 * i + 1];
            hi[i] = pk_trunc(a, bb);
            lo[i] = pk_trunc(a - tr16(a), bb - tr16(bb));
        }
        int ng = qt * 64 + q;                               // token within bh
        int r = bh * 256 + (ng >> 3);                       // gemm2 row
        int cc = (ng & 7) * 64 + dc;                        // gemm2 col (octet-aligned)
        int mt = r >> 4, m = r & 15, kc = cc >> 5, oct = (cc >> 3) & 3;
        unsigned short* fb_ = Ofrag + ((size_t)(mt * 16 + kc) * 2) * 512 + (m + 16 * oct) * 8;
        *(uint4*)fb_ = make_uint4(hi[0], hi[1], hi[2], hi[3]);
        *(uint4*)(fb_ + 512) = make_uint4(lo[0], lo[1], lo[2], lo[3]);
    }
}

// ---------------------------------------------------------------------------
// GEMM2: barrier-free, zero-LDS. Block = 128 rows x 64 cols; 8 waves
// (wm4 x wn2), each 2 mt x 2 nt. grid (8, 32). out = Ofrag @ wpfrag + bias.
// ---------------------------------------------------------------------------
__global__ __launch_bounds__(512, 4) void gemm_proj(const unsigned short* __restrict__ Ofrag,
                                                    const unsigned short* __restrict__ wpfrag,
                                                    const float* __restrict__ bias,
                                                    float* __restrict__ out)
{
    const int tid = threadIdx.x, lane = tid & 63, w = tid >> 6;
    const int l15 = lane & 15, l4 = lane >> 4;
    const int wm = w >> 1, wn = w & 1;
    const int row0 = blockIdx.y * 128, col0 = blockIdx.x * 64;
    const int mt0 = (row0 >> 4) + wm * 2;
    const int nt0 = (col0 >> 4) + wn * 2;

    floatx4 acc[2][2];
    #pragma unroll
    for (int i = 0; i < 2; ++i)
        #pragma unroll
        for (int j = 0; j < 2; ++j)
            #pragma unroll
            for (int r = 0; r < 4; ++r) acc[i][j][r] = 0.f;

    const unsigned short* ab = Ofrag + (size_t)lane * 8;
    const unsigned short* wb = wpfrag + (size_t)lane * 8;

    #pragma unroll
    for (int kc = 0; kc < 16; ++kc) {
        short8 bf[2][2];
        #pragma unroll
        for (int nt = 0; nt < 2; ++nt) {
            size_t fb_ = ((size_t)((nt0 + nt) * 16 + kc) * 2) * 512;
            bf[nt][0] = bcs8(*(const uint4*)(wb + fb_));
            bf[nt][1] = bcs8(*(const uint4*)(wb + fb_ + 512));
        }
        #pragma unroll
        for (int mt = 0; mt < 2; ++mt) {
            size_t fa_ = ((size_t)((mt0 + mt) * 16 + kc) * 2) * 512;
            short8 ah = bcs8(*(const uint4*)(ab + fa_));
            short8 al = bcs8(*(const uint4*)(ab + fa_ + 512));
            #pragma unroll
            for (int nt = 0; nt < 2; ++nt) {
                acc[mt][nt] = mfma16(ah, bf[nt][0], acc[mt][nt]);
                acc[mt][nt] = mfma16(ah, bf[nt][1], acc[mt][nt]);
                acc[mt][nt] = mfma16(al, bf[nt][0], acc[mt][nt]);
            }
        }
    }
    #pragma unroll
    for (int mt = 0; mt < 2; ++mt)
        #pragma unroll
        for (int nt = 0; nt < 2; ++nt) {
            int c = col0 + wn * 32 + nt * 16 + l15;
            float bv = bias[c];
            #pragma unroll
            for (int r = 0; r < 4; ++r) {
                int tok = row0 + wm * 32 + mt * 16 + l4 * 4 + r;
                out[(size_t)tok * 512 + c] = acc[mt][nt][r] + bv;
            }
        }
}

// ---------------------------------------------------------------------------
extern "C" void kernel_launch(void* const* d_in, const int* in_sizes, int n_in,
                              void* d_out, int out_size, void* d_ws, size_t ws_size,
                              hipStream_t stream)
{
    const float* x      = (const float*)d_in[0];
    const float* qkv_w  = (const float*)d_in[1];
    const float* proj_w = (const float*)d_in[2];
    const float* proj_b = (const float*)d_in[3];
    float* out = (float*)d_out;

    char* ws = (char*)d_ws;
    unsigned short* xfrag  = (unsigned short*)ws;                     //  8 MiB
    unsigned short* wqfrag = (unsigned short*)(ws + 8388608);         //  3 MiB
    unsigned short* wpfrag = (unsigned short*)(ws + 11534336);        //  1 MiB
    unsigned short* qd     = (unsigned short*)(ws + 12582912);        //  4 MiB
    unsigned short* kfrag  = (unsigned short*)(ws + 16777216);        //  4 MiB
    unsigned short* vfrag  = (unsigned short*)(ws + 20971520);        //  4 MiB
    unsigned short* Ofrag  = (unsigned short*)(ws + 25165824);        //  8 MiB (end 32 MiB)

    prep<<<512, 256, 0, stream>>>(qkv_w, proj_w, x, wqfrag, wpfrag, xfrag);
    gemm_qkv<<<dim3(12, 32), 512, 0, stream>>>(xfrag, wqfrag, qd, kfrag, vfrag);
    attn<<<512, 512, 0, stream>>>(qd, kfrag, vfrag, Ofrag);
    gemm_proj<<<dim3(8, 32), 512, 0, stream>>>(Ofrag, wpfrag, proj_b, out);
}